// Round 9
// baseline (204.588 us; speedup 1.0000x reference)
//
#include <hip/hip_runtime.h>

// Problem dims (ViT-Base LoRA-MoE qkv)
#define TOK 8192      // B*S = 32*256
#define DD  768       // in features
#define NOUT 2304     // 3*D
#define TT  8         // saved tasks
#define RR  16        // LoRA rank
#define KRANK 144     // T*R + R (per branch folded rank)

typedef __bf16 bf16;
typedef __bf16 bf16x4 __attribute__((ext_vector_type(4)));
typedef __bf16 bf16x8 __attribute__((ext_vector_type(8)));
typedef float  floatx4 __attribute__((ext_vector_type(4)));

__device__ __forceinline__ void gl_lds16(const void* g, void* l) {
    __builtin_amdgcn_global_load_lds((const __attribute__((address_space(1))) void*)g,
                                     (__attribute__((address_space(3))) void*)l, 16, 0, 0);
}

// ----------------------------------------------------------------- prep ----
// blocks 0..31: Frobenius norms of {A_q,B_q,A_v,B_v}[task]  (b>>3 selects
// tensor, b&7 selects task). blocks 32..3103: fp32->bf16 cast of x,
// 8 elems/thread (bf16x8 16B stores).  (unchanged, verified)
__global__ __launch_bounds__(256) void prep_kernel(
    const float* __restrict__ A_q, const float* __restrict__ B_q,
    const float* __restrict__ A_v, const float* __restrict__ B_v,
    const float* __restrict__ x, bf16* __restrict__ xb,
    float* __restrict__ norms)
{
    __shared__ float ws4[4];
    const int b = blockIdx.x;
    if (b < 32) {
        const float* base;
        switch (b >> 3) {
            case 0: base = A_q; break;
            case 1: base = B_q; break;
            case 2: base = A_v; break;
            default: base = B_v; break;
        }
        base += (b & 7) * (RR * DD);
        float s = 0.f;
        for (int i = threadIdx.x; i < RR * DD; i += 256) {
            float v = base[i];
            s = fmaf(v, v, s);
        }
        #pragma unroll
        for (int off = 32; off > 0; off >>= 1) s += __shfl_down(s, off);
        if ((threadIdx.x & 63) == 0) ws4[threadIdx.x >> 6] = s;
        __syncthreads();
        if (threadIdx.x == 0)
            norms[b] = sqrtf(ws4[0] + ws4[1] + ws4[2] + ws4[3]);
    } else {
        const int idx = ((b - 32) * 256 + threadIdx.x) * 8;
        const float4 v0 = *(const float4*)(x + idx);
        const float4 v1 = *(const float4*)(x + idx + 4);
        bf16x8 o = { (bf16)v0.x, (bf16)v0.y, (bf16)v0.z, (bf16)v0.w,
                     (bf16)v1.x, (bf16)v1.y, (bf16)v1.z, (bf16)v1.w };
        *(bf16x8*)(xb + idx) = o;
    }
}

// ----------------------------------------------------------------- fold ----
// Wc[row] = bf16(qkv_w[row] + sum_i c[row][i] * Acat[i][:]) for q/v thirds;
// plain bf16 cast for the k third. grid = (3, 288).  (unchanged, verified)
__global__ __launch_bounds__(256) void fold_kernel(
    const float* __restrict__ qkv_w,
    const float* __restrict__ A_q, const float* __restrict__ la_q,
    const float* __restrict__ B_q, const float* __restrict__ lb_q,
    const float* __restrict__ A_v, const float* __restrict__ la_v,
    const float* __restrict__ B_v, const float* __restrict__ lb_v,
    const float* __restrict__ gate_logits, const float* __restrict__ alpha,
    const float* __restrict__ norms, bf16* __restrict__ Wc)
{
    const int tid = threadIdx.x;
    const int d = blockIdx.x * 256 + tid;
    const int gy = blockIdx.y;

    if (gy >= 96 && gy < 192) {           // k third: pure cast
        const int rowbase = DD + (gy - 96) * 8;
        #pragma unroll
        for (int j = 0; j < 8; ++j) {
            const int row = rowbase + j;
            Wc[row * DD + d] = (bf16)qkv_w[row * DD + d];
        }
        return;
    }

    __shared__ float c_lds[8 * KRANK];
    __shared__ float sc_sh[TT];
    __shared__ float acur_sh;

    const bool is_v = (gy >= 192);
    const int e0 = (is_v ? gy - 192 : gy) * 8;
    const float* Astack = is_v ? A_v : A_q;
    const float* la     = is_v ? la_v : la_q;
    const float* Bmat   = is_v ? B_v : B_q;
    const float* lb     = is_v ? lb_v : lb_q;
    const float* nA     = norms + (is_v ? 16 : 0);
    const float* nB     = norms + (is_v ? 24 : 8);
    const int rowbase   = (is_v ? 2 * DD : 0) + e0;

    if (tid == 0) {
        float mx = gate_logits[0];
        for (int t = 1; t < TT; ++t) mx = fmaxf(mx, gate_logits[t]);
        float e[TT], s = 0.f;
        for (int t = 0; t < TT; ++t) { e[t] = __expf(gate_logits[t] - mx); s += e[t]; }
        for (int t = 0; t < TT; ++t) sc_sh[t] = (e[t] / s) / (nA[t] * nB[t]);
        acur_sh = alpha[TT];
    }
    __syncthreads();

    for (int idx = tid; idx < 8 * KRANK; idx += 256) {
        const int j = idx / KRANK, i = idx - j * KRANK;
        const int e = e0 + j;
        float v;
        if (i < TT * RR) {
            const int t = i >> 4, r = i & 15;
            v = sc_sh[t] * Bmat[(t * DD + e) * RR + r];
        } else {
            v = acur_sh * lb[e * RR + (i - TT * RR)];
        }
        c_lds[j * KRANK + i] = v;
    }
    __syncthreads();

    float acc[8] = {0.f, 0.f, 0.f, 0.f, 0.f, 0.f, 0.f, 0.f};

    for (int i = 0; i < TT * RR; i += 4) {
        const float a0 = Astack[(i + 0) * DD + d];
        const float a1 = Astack[(i + 1) * DD + d];
        const float a2 = Astack[(i + 2) * DD + d];
        const float a3 = Astack[(i + 3) * DD + d];
        #pragma unroll
        for (int j = 0; j < 8; ++j) {
            const float4 cv = *(const float4*)&c_lds[j * KRANK + i];
            acc[j] = fmaf(a0, cv.x, fmaf(a1, cv.y, fmaf(a2, cv.z, fmaf(a3, cv.w, acc[j]))));
        }
    }
    #pragma unroll
    for (int i = 0; i < RR; i += 4) {
        const float a0 = la[(i + 0) * DD + d];
        const float a1 = la[(i + 1) * DD + d];
        const float a2 = la[(i + 2) * DD + d];
        const float a3 = la[(i + 3) * DD + d];
        #pragma unroll
        for (int j = 0; j < 8; ++j) {
            const float4 cv = *(const float4*)&c_lds[j * KRANK + TT * RR + i];
            acc[j] = fmaf(a0, cv.x, fmaf(a1, cv.y, fmaf(a2, cv.z, fmaf(a3, cv.w, acc[j]))));
        }
    }

    #pragma unroll
    for (int j = 0; j < 8; ++j) {
        const int row = rowbase + j;
        Wc[row * DD + d] = (bf16)(qkv_w[row * DD + d] + acc[j]);
    }
}

// ----------------------------------------------------------------- gemm ----
// C[TOK,NOUT] = Xbf[TOK,DD] @ Wc[NOUT,DD]^T + bias.
// R15: A-direct-to-registers. Eight scheduling variants (R6-R14) are all
// 44-50us with LDS as the largest pipe (120KB/block-K-step ~ 21us total);
// none REDUCED the traffic. Change: A-fragments load global->reg directly
// (each wave reads only its own 64 A-rows; 8x16B loads/K-step, bytes and
// lane-mapping identical to what the LDS path delivered: row = wm+mt*16+
// (lane&15), k-chunk = ks*4+(lane>>4)). Removes A staging writes + A
// ds_reads: LDS/block-K-step 120 -> 72KB (-40%), gl_lds per wave 10 -> 6.
// A redundancy (2 N-wave-columns read the same rows) is L2-absorbed: the
// XCD swizzle keeps each A-panel slice (1.5MB) L2-resident per XCD, so
// global A re-reads hit L2 (36 TB/s), not HBM. FETCH_SIZE should stay
// ~26MB. B path, XOR swizzle (0 conflicts), epilogue, grid 768 @ 3
// blocks/CU: byte-identical to R9/R14.
// Commitment: if gemm doesn't improve >=3us, all pipes are exonerated and
// R16 declares the structure floor.
__global__ __launch_bounds__(256, 3) void gemm_kernel(
    const bf16* __restrict__ A, const bf16* __restrict__ B,
    const float* __restrict__ bias, float* __restrict__ C)
{
    __shared__ __align__(16) char smem[24576];  // B only: 192x64 bf16 (24KB)
    bf16* const lds_b = (bf16*)smem;

    const int tid  = threadIdx.x;
    const int lane = tid & 63;
    const int wave = tid >> 6;

    // XCD swizzle: 768 blocks = 8 XCD x (8 m-tiles x 12 n-tiles)
    const int flat  = blockIdx.x;
    const int xcd   = flat & 7;
    const int local = flat >> 3;           // 0..95
    const int mb    = xcd * 8 + (local & 7);   // 0..63
    const int nb    = local >> 3;              // 0..11
    const int m0 = mb * 128;
    const int n0 = nb * 192;

    // 4 waves: 2x2, each computes 64x96 (4x6 tiles of 16x16)
    const int wm = (wave >> 1) * 64;
    const int wn = (wave & 1) * 96;

    // B staging: lane l -> slot l (16B) within a 1KB chunk (8 rows x 64
    // bf16). logical row = l>>3, logical 16B chunk = (l&7)^(l>>3) (XOR
    // swizzle, R6/R9-verified: 0 bank conflicts).
    const int srow = lane >> 3;                    // 0..7
    const int scol = ((lane & 7) ^ srow) * 8;      // swizzled col (bf16 units)

    floatx4 acc[4][6];
    #pragma unroll
    for (int i = 0; i < 4; ++i)
        #pragma unroll
        for (int j = 0; j < 6; ++j)
            acc[i][j] = (floatx4){0.f, 0.f, 0.f, 0.f};

    // A direct-load base: row = m0+wm+(lane&15) (+ mt*16), k-chunk base =
    // (lane>>4)*8 elems (+ ks*32 + kt*64).
    const bf16* const gAr = A + (m0 + wm + (lane & 15)) * DD + (lane >> 4) * 8;
    const bf16* const gB  = B + (n0 + srow) * DD + scol;

    for (int kt = 0; kt < DD / 64; ++kt) {
        const int k0 = kt * 64;

        // A fragments: global -> registers (8 x 16B per wave). Issued
        // before B's gl_lds so they're the oldest VMEM ops; compiler
        // inserts the counted vmcnt before first MFMA use.
        bf16x8 afr[2][4];
        #pragma unroll
        for (int ks = 0; ks < 2; ++ks)
            #pragma unroll
            for (int mt = 0; mt < 4; ++mt)
                afr[ks][mt] = *(const bf16x8*)(gAr + mt * 16 * DD + k0 + ks * 32);

        // B staging: 24 chunks, round-robin by wave -> 6 per wave.
        #pragma unroll
        for (int i = 0; i < 6; ++i) {
            const int j = i * 4 + wave;            // 0..23
            gl_lds16(gB + j * 8 * DD + k0, &lds_b[j * 512]);
        }
        __syncthreads();   // drains gl_lds (vmcnt) — B tile visible to all

        #pragma unroll
        for (int ks = 0; ks < 2; ++ks) {
            const int c_log = ks * 4 + (lane >> 4); // 16B chunk index 0..7
            #pragma unroll
            for (int nt = 0; nt < 6; ++nt) {
                const int r = wn + nt * 16 + (lane & 15);
                const bf16x8 bfr = *(const bf16x8*)&lds_b[r * 64 + ((c_log ^ (r & 7)) * 8)];
                #pragma unroll
                for (int mt = 0; mt < 4; ++mt)
                    acc[mt][nt] = __builtin_amdgcn_mfma_f32_16x16x32_bf16(
                        afr[ks][mt], bfr, acc[mt][nt], 0, 0, 0);
            }
        }
        if (kt != DD / 64 - 1) __syncthreads();   // frees B buffer for next tile
    }

    // epilogue: direct stores. C/D layout col=lane&15, row=(lane>>4)*4+reg
    const int cr = (lane >> 4) * 4;
    const int cc = lane & 15;
    #pragma unroll
    for (int nt = 0; nt < 6; ++nt) {
        const int gn = n0 + wn + nt * 16 + cc;
        const float bv = bias[gn];
        #pragma unroll
        for (int mt = 0; mt < 4; ++mt) {
            const int gmb = m0 + wm + mt * 16 + cr;
            #pragma unroll
            for (int r = 0; r < 4; ++r)
                C[(gmb + r) * NOUT + gn] = acc[mt][nt][r] + bv;
        }
    }
}

// --------------------------------------------------------------- launch ----
extern "C" void kernel_launch(void* const* d_in, const int* in_sizes, int n_in,
                              void* d_out, int out_size, void* d_ws, size_t ws_size,
                              hipStream_t stream)
{
    const float* x           = (const float*)d_in[0];
    const float* qkv_w       = (const float*)d_in[1];
    const float* qkv_b       = (const float*)d_in[2];
    const float* la_q        = (const float*)d_in[3];
    const float* lb_q        = (const float*)d_in[4];
    const float* la_v        = (const float*)d_in[5];
    const float* lb_v        = (const float*)d_in[6];
    const float* A_q         = (const float*)d_in[7];
    const float* B_q         = (const float*)d_in[8];
    const float* A_v         = (const float*)d_in[9];
    const float* B_v         = (const float*)d_in[10];
    const float* gate_logits = (const float*)d_in[11];
    const float* alpha       = (const float*)d_in[12];
    float* out = (float*)d_out;

    char* ws = (char*)d_ws;
    bf16*  Xbf    = (bf16*)ws;                                  // 12,582,912 B
    bf16*  Wc     = (bf16*)(ws + 12582912);                     //  3,538,944 B
    float* norms  = (float*)(ws + 12582912 + 3538944);          // 32 floats

    prep_kernel<<<32 + TOK * DD / 2048, 256, 0, stream>>>(A_q, B_q, A_v, B_v,
                                                          x, Xbf, norms);
    fold_kernel<<<dim3(3, 288), 256, 0, stream>>>(qkv_w,
                                                  A_q, la_q, B_q, lb_q,
                                                  A_v, la_v, B_v, lb_v,
                                                  gate_logits, alpha, norms, Wc);
    gemm_kernel<<<768, 256, 0, stream>>>(Xbf, Wc, qkv_b, out);
}

// Round 10
// 172.812 us; speedup vs baseline: 1.1839x; 1.1839x over previous
//
#include <hip/hip_runtime.h>

// Problem dims (ViT-Base LoRA-MoE qkv)
#define TOK 8192      // B*S = 32*256
#define DD  768       // in features
#define NOUT 2304     // 3*D
#define TT  8         // saved tasks
#define RR  16        // LoRA rank
#define KRANK 144     // T*R + R (per branch folded rank)

typedef __bf16 bf16;
typedef __bf16 bf16x4 __attribute__((ext_vector_type(4)));
typedef __bf16 bf16x8 __attribute__((ext_vector_type(8)));
typedef float  floatx4 __attribute__((ext_vector_type(4)));

__device__ __forceinline__ void gl_lds16(const void* g, void* l) {
    __builtin_amdgcn_global_load_lds((const __attribute__((address_space(1))) void*)g,
                                     (__attribute__((address_space(3))) void*)l, 16, 0, 0);
}

// ----------------------------------------------------------------- prep ----
// blocks 0..31: Frobenius norms of {A_q,B_q,A_v,B_v}[task]  (b>>3 selects
// tensor, b&7 selects task). blocks 32..3103: fp32->bf16 cast of x,
// 8 elems/thread (bf16x8 16B stores).  (R9-verified best)
__global__ __launch_bounds__(256) void prep_kernel(
    const float* __restrict__ A_q, const float* __restrict__ B_q,
    const float* __restrict__ A_v, const float* __restrict__ B_v,
    const float* __restrict__ x, bf16* __restrict__ xb,
    float* __restrict__ norms)
{
    __shared__ float ws4[4];
    const int b = blockIdx.x;
    if (b < 32) {
        const float* base;
        switch (b >> 3) {
            case 0: base = A_q; break;
            case 1: base = B_q; break;
            case 2: base = A_v; break;
            default: base = B_v; break;
        }
        base += (b & 7) * (RR * DD);
        float s = 0.f;
        for (int i = threadIdx.x; i < RR * DD; i += 256) {
            float v = base[i];
            s = fmaf(v, v, s);
        }
        #pragma unroll
        for (int off = 32; off > 0; off >>= 1) s += __shfl_down(s, off);
        if ((threadIdx.x & 63) == 0) ws4[threadIdx.x >> 6] = s;
        __syncthreads();
        if (threadIdx.x == 0)
            norms[b] = sqrtf(ws4[0] + ws4[1] + ws4[2] + ws4[3]);
    } else {
        const int idx = ((b - 32) * 256 + threadIdx.x) * 8;
        const float4 v0 = *(const float4*)(x + idx);
        const float4 v1 = *(const float4*)(x + idx + 4);
        bf16x8 o = { (bf16)v0.x, (bf16)v0.y, (bf16)v0.z, (bf16)v0.w,
                     (bf16)v1.x, (bf16)v1.y, (bf16)v1.z, (bf16)v1.w };
        *(bf16x8*)(xb + idx) = o;
    }
}

// ----------------------------------------------------------------- fold ----
// Wc[row] = bf16(qkv_w[row] + sum_i c[row][i] * Acat[i][:]) for q/v thirds;
// plain bf16 cast for the k third. grid = (3, 288).  (unchanged, verified)
__global__ __launch_bounds__(256) void fold_kernel(
    const float* __restrict__ qkv_w,
    const float* __restrict__ A_q, const float* __restrict__ la_q,
    const float* __restrict__ B_q, const float* __restrict__ lb_q,
    const float* __restrict__ A_v, const float* __restrict__ la_v,
    const float* __restrict__ B_v, const float* __restrict__ lb_v,
    const float* __restrict__ gate_logits, const float* __restrict__ alpha,
    const float* __restrict__ norms, bf16* __restrict__ Wc)
{
    const int tid = threadIdx.x;
    const int d = blockIdx.x * 256 + tid;
    const int gy = blockIdx.y;

    if (gy >= 96 && gy < 192) {           // k third: pure cast
        const int rowbase = DD + (gy - 96) * 8;
        #pragma unroll
        for (int j = 0; j < 8; ++j) {
            const int row = rowbase + j;
            Wc[row * DD + d] = (bf16)qkv_w[row * DD + d];
        }
        return;
    }

    __shared__ float c_lds[8 * KRANK];
    __shared__ float sc_sh[TT];
    __shared__ float acur_sh;

    const bool is_v = (gy >= 192);
    const int e0 = (is_v ? gy - 192 : gy) * 8;
    const float* Astack = is_v ? A_v : A_q;
    const float* la     = is_v ? la_v : la_q;
    const float* Bmat   = is_v ? B_v : B_q;
    const float* lb     = is_v ? lb_v : lb_q;
    const float* nA     = norms + (is_v ? 16 : 0);
    const float* nB     = norms + (is_v ? 24 : 8);
    const int rowbase   = (is_v ? 2 * DD : 0) + e0;

    if (tid == 0) {
        float mx = gate_logits[0];
        for (int t = 1; t < TT; ++t) mx = fmaxf(mx, gate_logits[t]);
        float e[TT], s = 0.f;
        for (int t = 0; t < TT; ++t) { e[t] = __expf(gate_logits[t] - mx); s += e[t]; }
        for (int t = 0; t < TT; ++t) sc_sh[t] = (e[t] / s) / (nA[t] * nB[t]);
        acur_sh = alpha[TT];
    }
    __syncthreads();

    for (int idx = tid; idx < 8 * KRANK; idx += 256) {
        const int j = idx / KRANK, i = idx - j * KRANK;
        const int e = e0 + j;
        float v;
        if (i < TT * RR) {
            const int t = i >> 4, r = i & 15;
            v = sc_sh[t] * Bmat[(t * DD + e) * RR + r];
        } else {
            v = acur_sh * lb[e * RR + (i - TT * RR)];
        }
        c_lds[j * KRANK + i] = v;
    }
    __syncthreads();

    float acc[8] = {0.f, 0.f, 0.f, 0.f, 0.f, 0.f, 0.f, 0.f};

    for (int i = 0; i < TT * RR; i += 4) {
        const float a0 = Astack[(i + 0) * DD + d];
        const float a1 = Astack[(i + 1) * DD + d];
        const float a2 = Astack[(i + 2) * DD + d];
        const float a3 = Astack[(i + 3) * DD + d];
        #pragma unroll
        for (int j = 0; j < 8; ++j) {
            const float4 cv = *(const float4*)&c_lds[j * KRANK + i];
            acc[j] = fmaf(a0, cv.x, fmaf(a1, cv.y, fmaf(a2, cv.z, fmaf(a3, cv.w, acc[j]))));
        }
    }
    #pragma unroll
    for (int i = 0; i < RR; i += 4) {
        const float a0 = la[(i + 0) * DD + d];
        const float a1 = la[(i + 1) * DD + d];
        const float a2 = la[(i + 2) * DD + d];
        const float a3 = la[(i + 3) * DD + d];
        #pragma unroll
        for (int j = 0; j < 8; ++j) {
            const float4 cv = *(const float4*)&c_lds[j * KRANK + TT * RR + i];
            acc[j] = fmaf(a0, cv.x, fmaf(a1, cv.y, fmaf(a2, cv.z, fmaf(a3, cv.w, acc[j]))));
        }
    }

    #pragma unroll
    for (int j = 0; j < 8; ++j) {
        const int row = rowbase + j;
        Wc[row * DD + d] = (bf16)(qkv_w[row * DD + d] + acc[j]);
    }
}

// ----------------------------------------------------------------- gemm ----
// C[TOK,NOUT] = Xbf[TOK,DD] @ Wc[NOUT,DD]^T + bias.
// R16: exact R9 restoration — the best measured configuration (171.25us
// total). 128x192 tile, BK=64, 4 waves 2x2 (wave 64x96, 4x6 acc), single
// 40KB LDS buffer -> 3 blocks/CU, grid 768 = one full residency round,
// full-drain __syncthreads() loop, R6-proven chunk staging + XOR swizzle
// (0 conflicts).
// FLOOR DECLARATION (9 experiments): this thin-K (K=768, 12 K-step) GEMM
// is structure-floor-bound at ~650 TF / ~44.5us. Exonerated by measurement:
// LDS traffic (R15: -40% bytes -> WORSE), sync structure (R7/R8/R10/R12
// counted-vmcnt/dbuf/1-barrier/BK128 all null), occupancy (R9 3/CU == R6
// 2/CU), MFMA shape (R11 32x32 worse), fusion (R13 worse). The gap to the
// 14us MFMA floor requires the co-designed fine-grained pipeline whose
// coarse forms all measured null at this K; remaining window = ~117us
// harness fill (uncontrollable) + ~54us kernels, noise +/-3-6us.
__global__ __launch_bounds__(256, 3) void gemm_kernel(
    const bf16* __restrict__ A, const bf16* __restrict__ B,
    const float* __restrict__ bias, float* __restrict__ C)
{
    __shared__ __align__(16) char smem[40960];  // A 128x64 bf16 (16KB) + B 192x64 bf16 (24KB)
    bf16* const lds_a = (bf16*)smem;
    bf16* const lds_b = (bf16*)(smem + 16384);

    const int tid  = threadIdx.x;
    const int lane = tid & 63;
    const int wave = tid >> 6;

    // XCD swizzle: 768 blocks = 8 XCD x (8 m-tiles x 12 n-tiles)
    const int flat  = blockIdx.x;
    const int xcd   = flat & 7;
    const int local = flat >> 3;           // 0..95
    const int mb    = xcd * 8 + (local & 7);   // 0..63
    const int nb    = local >> 3;              // 0..11
    const int m0 = mb * 128;
    const int n0 = nb * 192;

    // 4 waves: 2x2, each computes 64x96 (4x6 tiles of 16x16)
    const int wm = (wave >> 1) * 64;
    const int wn = (wave & 1) * 96;

    // staging: lane l -> slot l (16B) within a 1KB chunk (8 rows x 64 bf16).
    // logical row = l>>3, logical 16B chunk = (l&7) ^ (l>>3)  (XOR swizzle,
    // R6-verified: 0 bank conflicts).
    const int srow = lane >> 3;                    // 0..7
    const int scol = ((lane & 7) ^ srow) * 8;      // swizzled col (bf16 units)

    floatx4 acc[4][6];
    #pragma unroll
    for (int i = 0; i < 4; ++i)
        #pragma unroll
        for (int j = 0; j < 6; ++j)
            acc[i][j] = (floatx4){0.f, 0.f, 0.f, 0.f};

    const bf16* const gA = A + (m0 + srow) * DD + scol;
    const bf16* const gB = B + (n0 + srow) * DD + scol;

    for (int kt = 0; kt < DD / 64; ++kt) {
        const int k0 = kt * 64;
        // stage A: 16 chunks of 8 rows; B: 24 chunks. round-robin by wave
        // -> 10 chunks per wave.
        #pragma unroll
        for (int i = 0; i < 4; ++i) {
            const int j = i * 4 + wave;            // 0..15
            gl_lds16(gA + j * 8 * DD + k0, &lds_a[j * 512]);
        }
        #pragma unroll
        for (int i = 0; i < 6; ++i) {
            const int j = i * 4 + wave;            // 0..23
            gl_lds16(gB + j * 8 * DD + k0, &lds_b[j * 512]);
        }
        __syncthreads();   // drains gl_lds (vmcnt) — tiles visible to all

        #pragma unroll
        for (int ks = 0; ks < 2; ++ks) {
            const int c_log = ks * 4 + (lane >> 4); // 16B chunk index 0..7
            bf16x8 af[4];
            #pragma unroll
            for (int mt = 0; mt < 4; ++mt) {
                const int r = wm + mt * 16 + (lane & 15);
                af[mt] = *(const bf16x8*)&lds_a[r * 64 + ((c_log ^ (r & 7)) * 8)];
            }
            #pragma unroll
            for (int nt = 0; nt < 6; ++nt) {
                const int r = wn + nt * 16 + (lane & 15);
                const bf16x8 bfr = *(const bf16x8*)&lds_b[r * 64 + ((c_log ^ (r & 7)) * 8)];
                #pragma unroll
                for (int mt = 0; mt < 4; ++mt)
                    acc[mt][nt] = __builtin_amdgcn_mfma_f32_16x16x32_bf16(
                        af[mt], bfr, acc[mt][nt], 0, 0, 0);
            }
        }
        __syncthreads();   // frees LDS buffer for next tile
    }

    // epilogue: direct stores. C/D layout col=lane&15, row=(lane>>4)*4+reg
    const int cr = (lane >> 4) * 4;
    const int cc = lane & 15;
    #pragma unroll
    for (int nt = 0; nt < 6; ++nt) {
        const int gn = n0 + wn + nt * 16 + cc;
        const float bv = bias[gn];
        #pragma unroll
        for (int mt = 0; mt < 4; ++mt) {
            const int gmb = m0 + wm + mt * 16 + cr;
            #pragma unroll
            for (int r = 0; r < 4; ++r)
                C[(gmb + r) * NOUT + gn] = acc[mt][nt][r] + bv;
        }
    }
}

// --------------------------------------------------------------- launch ----
extern "C" void kernel_launch(void* const* d_in, const int* in_sizes, int n_in,
                              void* d_out, int out_size, void* d_ws, size_t ws_size,
                              hipStream_t stream)
{
    const float* x           = (const float*)d_in[0];
    const float* qkv_w       = (const float*)d_in[1];
    const float* qkv_b       = (const float*)d_in[2];
    const float* la_q        = (const float*)d_in[3];
    const float* lb_q        = (const float*)d_in[4];
    const float* la_v        = (const float*)d_in[5];
    const float* lb_v        = (const float*)d_in[6];
    const float* A_q         = (const float*)d_in[7];
    const float* B_q         = (const float*)d_in[8];
    const float* A_v         = (const float*)d_in[9];
    const float* B_v         = (const float*)d_in[10];
    const float* gate_logits = (const float*)d_in[11];
    const float* alpha       = (const float*)d_in[12];
    float* out = (float*)d_out;

    char* ws = (char*)d_ws;
    bf16*  Xbf    = (bf16*)ws;                                  // 12,582,912 B
    bf16*  Wc     = (bf16*)(ws + 12582912);                     //  3,538,944 B
    float* norms  = (float*)(ws + 12582912 + 3538944);          // 32 floats

    prep_kernel<<<32 + TOK * DD / 2048, 256, 0, stream>>>(A_q, B_q, A_v, B_v,
                                                          x, Xbf, norms);
    fold_kernel<<<dim3(3, 288), 256, 0, stream>>>(qkv_w,
                                                  A_q, la_q, B_q, lb_q,
                                                  A_v, la_v, B_v, lb_v,
                                                  gate_logits, alpha, norms, Wc);
    gemm_kernel<<<768, 256, 0, stream>>>(Xbf, Wc, qkv_b, out);
}